// Round 3
// baseline (8179.294 us; speedup 1.0000x reference)
//
#include <hip/hip_runtime.h>
#include <type_traits>

// ---------------- types ----------------
typedef _Float16 half8 __attribute__((ext_vector_type(8)));
typedef _Float16 half4v __attribute__((ext_vector_type(4)));
typedef float f32x4 __attribute__((ext_vector_type(4)));

struct U128 { unsigned long long a, b; };

#define B_ 64
#define T_ 512
#define H_ 1024
#define G_ 4096      // 4*H
#define K_ 1024
#define MPROJ (B_ * T_)  // 32768

// ---------------- prep kernels ----------------
__global__ void k_f32_to_f16(const float* __restrict__ s, _Float16* __restrict__ d, int n4) {
  int i = blockIdx.x * 256 + threadIdx.x;
  if (i < n4) {
    float4 v = ((const float4*)s)[i];
    half4v o;
    o[0] = (_Float16)v.x; o[1] = (_Float16)v.y; o[2] = (_Float16)v.z; o[3] = (_Float16)v.w;
    ((half4v*)d)[i] = o;
  }
}

__global__ void k_bias(const float* __restrict__ bi0, const float* __restrict__ bh0,
                       const float* __restrict__ bi1, const float* __restrict__ bh1,
                       float* __restrict__ o0, float* __restrict__ o1) {
  int i = blockIdx.x * 256 + threadIdx.x;
  if (i < G_) { o0[i] = bi0[i] + bh0[i]; o1[i] = bi1[i] + bh1[i]; }
}

__global__ void k_zero(uint4* __restrict__ p, int n) {
  int i = blockIdx.x * 256 + threadIdx.x;
  if (i < n) p[i] = make_uint4(0u, 0u, 0u, 0u);
}

// ---------------- projection GEMM ----------------
// C[m][n] = sum_k A[m][k]*Bw[n][k] + bias[n], C stored fp16. M=32768, N=4096, K=1024.
// 128x128 tile, BK=32, 256 thr (4 waves, each a 64x64 quadrant of 4x4 16x16x32 MFMAs).
template <typename AT>
__global__ __launch_bounds__(256, 2) void k_proj(const AT* __restrict__ A,
                                                 const _Float16* __restrict__ Bw,
                                                 const float* __restrict__ bias,
                                                 _Float16* __restrict__ C) {
  const int NBN = G_ / 128;  // 32
  int bm = blockIdx.x / NBN;
  int bn = blockIdx.x % NBN;
  __shared__ __align__(16) _Float16 As[128 * 40];
  __shared__ __align__(16) _Float16 Bs[128 * 40];
  int tid = threadIdx.x;
  int lane = tid & 63, wave = tid >> 6;
  int wm = (wave >> 1) * 64, wn = (wave & 1) * 64;
  int quad = lane >> 4, l16 = lane & 15;
  f32x4 acc[4][4] = {};
  int r = tid >> 1;            // staged row 0..127
  int hc = (tid & 1) * 16;     // half-offset within BK=32
  const AT* aRow = A + (size_t)(bm * 128 + r) * K_ + hc;
  const _Float16* bRow = Bw + (size_t)(bn * 128 + r) * K_ + hc;
  _Float16* aDst = As + r * 40 + hc;
  _Float16* bDst = Bs + r * 40 + hc;

  for (int kt = 0; kt < K_ / 32; ++kt) {
    if constexpr (std::is_same<AT, float>::value) {
      float tmp[16];
      *(float4*)(tmp + 0)  = *(const float4*)(aRow + 0);
      *(float4*)(tmp + 4)  = *(const float4*)(aRow + 4);
      *(float4*)(tmp + 8)  = *(const float4*)(aRow + 8);
      *(float4*)(tmp + 12) = *(const float4*)(aRow + 12);
      half8 h0, h1;
#pragma unroll
      for (int e = 0; e < 8; ++e) { h0[e] = (_Float16)tmp[e]; h1[e] = (_Float16)tmp[e + 8]; }
      *(half8*)(aDst) = h0;
      *(half8*)(aDst + 8) = h1;
    } else {
      *(half8*)(aDst) = *(const half8*)(aRow);
      *(half8*)(aDst + 8) = *(const half8*)(aRow + 8);
    }
    *(half8*)(bDst) = *(const half8*)(bRow);
    *(half8*)(bDst + 8) = *(const half8*)(bRow + 8);
    __syncthreads();
    half8 af[4], bf[4];
#pragma unroll
    for (int i = 0; i < 4; ++i) af[i] = *(const half8*)(As + (wm + i * 16 + l16) * 40 + quad * 8);
#pragma unroll
    for (int j = 0; j < 4; ++j) bf[j] = *(const half8*)(Bs + (wn + j * 16 + l16) * 40 + quad * 8);
#pragma unroll
    for (int i = 0; i < 4; ++i)
#pragma unroll
      for (int j = 0; j < 4; ++j)
        acc[i][j] = __builtin_amdgcn_mfma_f32_16x16x32_f16(af[i], bf[j], acc[i][j], 0, 0, 0);
    __syncthreads();
    aRow += 32;
    bRow += 32;
  }
  // epilogue: C/D layout m = quad*4+reg, n = lane&15
#pragma unroll
  for (int j = 0; j < 4; ++j) {
    int n = bn * 128 + wn + j * 16 + l16;
    float bv = bias[n];
#pragma unroll
    for (int i = 0; i < 4; ++i) {
      size_t m0 = (size_t)(bm * 128 + wm + i * 16 + quad * 4);
#pragma unroll
      for (int rr = 0; rr < 4; ++rr)
        C[(m0 + rr) * G_ + n] = (_Float16)(acc[i][j][rr] + bv);
    }
  }
}

// ---------------- persistent recurrence (barrier-free, tagged dataflow) ----------------
// 256 WGs x 512 thr (cooperative, 1 WG/CU). Group g = blockIdx&3 owns batch rows
// [16g,16g+16); WG wid = blockIdx>>2 owns hidden units [16*wid,16*wid+16), all 4 gates.
// W_hh slice in registers (K split 8 ways over waves); c state in LDS.
// h exchange: each h element is a 32-bit word (step_tag<<16 | fp16), stored/loaded
// agent-coherent. Consumers retry-load until tag == s. Ping-pong (tag s in buf[s&1])
// bounds inter-WG skew to 1 step, so overwrites are race-free. No barrier, no counter.
__global__ __launch_bounds__(512, 2) void k_rec(
    const _Float16* __restrict__ xg,   // [B*T][4H] fp16, includes both biases
    const _Float16* __restrict__ Whh,  // [4H][H] fp16
    unsigned* tb0, unsigned* tb1,      // tagged h buffers [B][H] dwords
    _Float16* __restrict__ out16,      // layer0: out0 buffer; layer1: null
    float* __restrict__ out32,         // layer1: d_out; layer0: null
    float* __restrict__ hn_out, float* __restrict__ cn_out) {
  int g = blockIdx.x & 3;
  int wid = blockIdx.x >> 2;
  int u0 = wid * 16;
  int b0 = g * 16;
  int tid = threadIdx.x;
  int lane = tid & 63, w = tid >> 6;
  int quad = lane >> 4, l16 = lane & 15;

  __shared__ float part[8][4][16][18];  // [wave][gate][m][n] fp32 partials (padded)
  __shared__ float red[4][16][18];      // reduced gates
  __shared__ float cs[16][16];          // cell state
  if (tid < 256) ((float*)cs)[tid] = 0.f;

  // resident W_hh fragments: wave w covers K-slice [128w, 128w+128)
  int ks = w * 128;
  half8 wf[4][4];
#pragma unroll
  for (int gt = 0; gt < 4; ++gt)
#pragma unroll
    for (int kk = 0; kk < 4; ++kk)
      wf[gt][kk] = *(const half8*)(Whh + (size_t)(gt * H_ + u0 + l16) * K_ + ks + kk * 32 + quad * 8);
  __syncthreads();

  int fm = (w & 3) * 4 + quad;  // finalization row for waves 0..3

  for (int s = 0; s < T_; ++s) {
    const unsigned* tagIn = (s & 1) ? tb1 : tb0;  // holds tag s
    unsigned* tagOut = (s & 1) ? tb0 : tb1;       // receives tag s+1

    // prefetch this step's xg early (plain loads, L2-cached)
    float pxi = 0.f, pxf = 0.f, pxg = 0.f, pxo = 0.f;
    if (w < 4) {
      const _Float16* xr = xg + ((size_t)(b0 + fm) * T_ + s) * G_ + u0 + l16;
      pxi = (float)xr[0];
      pxf = (float)xr[H_];
      pxg = (float)xr[2 * H_];
      pxo = (float)xr[3 * H_];
    }

    f32x4 acc[4] = {};
    const unsigned* hrow = tagIn + (size_t)(b0 + l16) * H_ + ks;
    unsigned stag = (unsigned)s;
#pragma unroll
    for (int kk = 0; kk < 4; ++kk) {
      const unsigned long long* p = (const unsigned long long*)(hrow + kk * 32 + quad * 8);
      unsigned d0, d1, d2, d3, d4, d5, d6, d7;
      for (;;) {
        unsigned long long q0 = __hip_atomic_load(p + 0, __ATOMIC_RELAXED, __HIP_MEMORY_SCOPE_AGENT);
        unsigned long long q1 = __hip_atomic_load(p + 1, __ATOMIC_RELAXED, __HIP_MEMORY_SCOPE_AGENT);
        unsigned long long q2 = __hip_atomic_load(p + 2, __ATOMIC_RELAXED, __HIP_MEMORY_SCOPE_AGENT);
        unsigned long long q3 = __hip_atomic_load(p + 3, __ATOMIC_RELAXED, __HIP_MEMORY_SCOPE_AGENT);
        d0 = (unsigned)q0; d1 = (unsigned)(q0 >> 32);
        d2 = (unsigned)q1; d3 = (unsigned)(q1 >> 32);
        d4 = (unsigned)q2; d5 = (unsigned)(q2 >> 32);
        d6 = (unsigned)q3; d7 = (unsigned)(q3 >> 32);
        unsigned bad = ((d0 >> 16) ^ stag) | ((d1 >> 16) ^ stag) |
                       ((d2 >> 16) ^ stag) | ((d3 >> 16) ^ stag) |
                       ((d4 >> 16) ^ stag) | ((d5 >> 16) ^ stag) |
                       ((d6 >> 16) ^ stag) | ((d7 >> 16) ^ stag);
        if (!__any((int)(bad != 0))) break;
        __builtin_amdgcn_s_sleep(1);
      }
      unsigned p0 = (d0 & 0xffffu) | (d1 << 16);
      unsigned p1 = (d2 & 0xffffu) | (d3 << 16);
      unsigned p2 = (d4 & 0xffffu) | (d5 << 16);
      unsigned p3 = (d6 & 0xffffu) | (d7 << 16);
      U128 u;
      u.a = (unsigned long long)p0 | ((unsigned long long)p1 << 32);
      u.b = (unsigned long long)p2 | ((unsigned long long)p3 << 32);
      half8 af = __builtin_bit_cast(half8, u);
#pragma unroll
      for (int gt = 0; gt < 4; ++gt)
        acc[gt] = __builtin_amdgcn_mfma_f32_16x16x32_f16(af, wf[gt][kk], acc[gt], 0, 0, 0);
    }
#pragma unroll
    for (int gt = 0; gt < 4; ++gt)
#pragma unroll
      for (int rr = 0; rr < 4; ++rr)
        part[w][gt][quad * 4 + rr][l16] = acc[gt][rr];
    __syncthreads();

    {  // cross-wave K reduction: wave w -> gate w&3, row-half w>>2
      int gt = w & 3, rh = w >> 2;
#pragma unroll
      for (int rr = 2 * rh; rr < 2 * rh + 2; ++rr) {
        int m = quad * 4 + rr;
        float sum = part[0][gt][m][l16];
#pragma unroll
        for (int w2 = 1; w2 < 8; ++w2) sum += part[w2][gt][m][l16];
        red[gt][m][l16] = sum;
      }
    }
    __syncthreads();

    if (w < 4) {  // finalization: 4 waves x 64 lanes = 256 (m,n) cells
      int m = fm, n = l16;
      float iv = red[0][m][n] + pxi;
      float fv = red[1][m][n] + pxf;
      float gv = red[2][m][n] + pxg;
      float ov = red[3][m][n] + pxo;
      float si = 1.f / (1.f + __expf(-iv));
      float sf = 1.f / (1.f + __expf(-fv));
      float so = 1.f / (1.f + __expf(-ov));
      float ag = fabsf(gv), eg = __expf(-2.f * ag);
      float tg = (1.f - eg) / (1.f + eg);
      tg = (gv < 0.f) ? -tg : tg;
      float c = sf * cs[m][n] + si * tg;
      cs[m][n] = c;
      float ac = fabsf(c), ec = __expf(-2.f * ac);
      float th = (1.f - ec) / (1.f + ec);
      th = (c < 0.f) ? -th : th;
      float h = so * th;
      // tagged h publish FIRST (critical path): (tag s+1 << 16) | fp16 bits
      unsigned short hu = __builtin_bit_cast(unsigned short, (_Float16)h);
      __hip_atomic_store(tagOut + (size_t)(b0 + m) * H_ + u0 + n,
                         ((unsigned)(s + 1) << 16) | (unsigned)hu,
                         __ATOMIC_RELAXED, __HIP_MEMORY_SCOPE_AGENT);
      size_t oidx = ((size_t)(b0 + m) * T_ + s) * H_ + u0 + n;
      if (out16) out16[oidx] = (_Float16)h;
      if (out32) out32[oidx] = h;
      if (s == T_ - 1) {
        hn_out[(size_t)(b0 + m) * H_ + u0 + n] = h;
        cn_out[(size_t)(b0 + m) * H_ + u0 + n] = c;
      }
    }
    // no barrier: next step's consumers self-synchronize on tags
  }
}

// ---------------- host ----------------
extern "C" void kernel_launch(void* const* d_in, const int* in_sizes, int n_in,
                              void* d_out, int out_size, void* d_ws, size_t ws_size,
                              hipStream_t stream) {
  (void)in_sizes; (void)n_in; (void)out_size;
  const float* X    = (const float*)d_in[0];
  const float* Wih0 = (const float*)d_in[1];
  const float* bih0 = (const float*)d_in[2];
  const float* Whh0 = (const float*)d_in[3];
  const float* bhh0 = (const float*)d_in[4];
  const float* Wih1 = (const float*)d_in[5];
  const float* bih1 = (const float*)d_in[6];
  const float* Whh1 = (const float*)d_in[7];
  const float* bhh1 = (const float*)d_in[8];
  float* out = (float*)d_out;
  char* ws = (char*)d_ws;

  // ws layout (bytes):
  constexpr size_t SZW = (size_t)G_ * K_ * 2;  // 8 MB per packed weight
  constexpr size_t OFF_B0   = 4 * SZW;                          // 33554432
  constexpr size_t OFF_B1   = OFF_B0 + 16384;
  constexpr size_t OFF_TAG  = OFF_B1 + 16384;                   // 33587200
  constexpr size_t SZTAG    = (size_t)B_ * H_ * 4;              // 256 KB per buffer
  constexpr size_t OFF_OUT0 = OFF_TAG + 2 * SZTAG;              // 34111488
  constexpr size_t OFF_XG   = OFF_OUT0 + (size_t)MPROJ * H_ * 2;  // 101220352
  constexpr size_t NEED     = OFF_XG + (size_t)MPROJ * G_ * 2;    // 369655808
  if (ws_size < NEED) return;  // fail visibly rather than corrupt

  _Float16* Wih0h = (_Float16*)(ws + 0 * SZW);
  _Float16* Whh0h = (_Float16*)(ws + 1 * SZW);
  _Float16* Wih1h = (_Float16*)(ws + 2 * SZW);
  _Float16* Whh1h = (_Float16*)(ws + 3 * SZW);
  float* b0s = (float*)(ws + OFF_B0);
  float* b1s = (float*)(ws + OFF_B1);
  unsigned* tb0 = (unsigned*)(ws + OFF_TAG);
  unsigned* tb1 = (unsigned*)(ws + OFF_TAG + SZTAG);
  _Float16* out0h = (_Float16*)(ws + OFF_OUT0);
  _Float16* xgp   = (_Float16*)(ws + OFF_XG);

  // prep: pack weights to fp16, fold biases, zero tagged h buffers (tag 0 = h_0 = 0)
  k_f32_to_f16<<<4096, 256, 0, stream>>>(Wih0, Wih0h, G_ * K_ / 4);
  k_f32_to_f16<<<4096, 256, 0, stream>>>(Whh0, Whh0h, G_ * K_ / 4);
  k_f32_to_f16<<<4096, 256, 0, stream>>>(Wih1, Wih1h, G_ * K_ / 4);
  k_f32_to_f16<<<4096, 256, 0, stream>>>(Whh1, Whh1h, G_ * K_ / 4);
  k_bias<<<16, 256, 0, stream>>>(bih0, bhh0, bih1, bhh1, b0s, b1s);
  k_zero<<<128, 256, 0, stream>>>((uint4*)(ws + OFF_TAG), (int)(2 * SZTAG / 16));

  const int projGrid = (MPROJ / 128) * (G_ / 128);  // 8192

  // layer 0
  k_proj<float><<<dim3(projGrid), dim3(256), 0, stream>>>(X, Wih0h, b0s, xgp);
  {
    const _Float16* a0 = xgp;
    const _Float16* a1 = Whh0h;
    unsigned* a2 = tb0;
    unsigned* a3 = tb1;
    _Float16* a4 = out0h;
    float* a5 = nullptr;
    float* a6 = out + 33554432;            // h_n[0]
    float* a7 = out + 33554432 + 131072;   // c_n[0]
    void* args[8] = {&a0, &a1, &a2, &a3, &a4, &a5, &a6, &a7};
    hipLaunchCooperativeKernel((void*)k_rec, dim3(256), dim3(512), args, 0, stream);
  }

  // re-zero tagged buffers between layers (layer-0 leftovers contain valid-looking tags)
  k_zero<<<128, 256, 0, stream>>>((uint4*)(ws + OFF_TAG), (int)(2 * SZTAG / 16));

  // layer 1
  k_proj<_Float16><<<dim3(projGrid), dim3(256), 0, stream>>>(out0h, Wih1h, b1s, xgp);
  {
    const _Float16* a0 = xgp;
    const _Float16* a1 = Whh1h;
    unsigned* a2 = tb0;
    unsigned* a3 = tb1;
    _Float16* a4 = nullptr;
    float* a5 = out;                               // out1
    float* a6 = out + 33554432 + 65536;            // h_n[1]
    float* a7 = out + 33554432 + 131072 + 65536;   // c_n[1]
    void* args[8] = {&a0, &a1, &a2, &a3, &a4, &a5, &a6, &a7};
    hipLaunchCooperativeKernel((void*)k_rec, dim3(256), dim3(512), args, 0, stream);
  }
}